// Round 10
// baseline (183.295 us; speedup 1.0000x reference)
//
#include <hip/hip_runtime.h>

#define GH 64
#define LS 32
#define HF 32
#define DS 16

// transcendental folding constants (exact fp32 rescale of weights at prep)
#define NLOG2E -1.4426950408889634f   // r,z columns:  sigm(x)=rcp(1+exp2(-log2e*x))
#define P2LOG2E 2.8853900817779268f   // n columns:    tanh(x)=1-2*rcp(exp2(2log2e*x)+1)

typedef short bf16x8 __attribute__((ext_vector_type(8)));
typedef float f32x4 __attribute__((ext_vector_type(4)));

#define MFMA16(a, b, c) __builtin_amdgcn_mfma_f32_16x16x32_bf16(a, b, c, 0, 0, 0)

__device__ __forceinline__ unsigned int f2bf_rne(float f) {
    unsigned int u = __float_as_uint(f);
    return (u + 0x7FFFu + ((u >> 16) & 1u)) >> 16;   // RNE (prep kernel only)
}
__device__ __forceinline__ unsigned short f2bf_h(float f) {
    return (unsigned short)((__float_as_uint(f) + 0x8000u) >> 16);  // half-up
}
__device__ __forceinline__ unsigned int pack_trunc(float v0, float v1) {
    return __builtin_amdgcn_perm(__float_as_uint(v1), __float_as_uint(v0),
                                 0x07060302u);   // (bf16(v1)<<16)|bf16(v0)
}
__device__ __forceinline__ bf16x8 as_frag(uint4 u) {
    union { uint4 a; bf16x8 b; } cv; cv.a = u; return cv.b;
}

// A-fragment from one 16x64 bf16 slot, XOR-swizzled 16B blocks:
// (seq,ch) at seq*64 + (((ch>>3)^(seq&7))<<3) + (ch&7).
__device__ __forceinline__ bf16x8 ld_afrag(const unsigned short* slot, int m,
                                           int quad, int half) {
    int b   = half * 4 + quad;
    int idx = (m << 6) + ((b ^ (m & 7)) << 3);
    return as_frag(*reinterpret_cast<const uint4*>(slot + idx));
}

// ---- prep (read-coalesced, verified R2): fp32 weights -> bf16 MFMA
// B-fragments, fragment-ordered, transcendental scales FOLDED IN. One
// thread per SOURCE element (coalesced reads, scattered fire-and-forget
// writes). Also zeroes `out` (removes a memset dispatch).
__global__ __launch_bounds__(256) void prep_weights(
    const float* __restrict__ Wih, const float* __restrict__ Whh,
    const float* __restrict__ soW, const float* __restrict__ s2sW,
    unsigned short* __restrict__ wsW,
    float* __restrict__ out, int out_n)
{
    int gid = blockIdx.x * 256 + threadIdx.x;
    int nthreads = gridDim.x * 256;

    // ---- zero the output buffer (float4 grid-stride + scalar tail) ----
    {
        float4* out4 = reinterpret_cast<float4*>(out);
        int n4 = out_n >> 2;
        for (int i = gid; i < n4; i += nthreads)
            out4[i] = make_float4(0.f, 0.f, 0.f, 0.f);
        int tail = out_n & 3;
        if (gid < tail) out[n4 * 4 + gid] = 0.0f;
    }

    if (gid >= 104 * 1024) return;

    float v;
    int dest;
    if (gid < 98304) {
        // GRU weights: source order (which, l, k, g) with g fastest (coalesced)
        int g     = gid % 192;
        int r1    = gid / 192;          // (which,l,k)
        int k     = r1 & 63;
        int r2    = r1 >> 6;            // (which,l)
        int l     = r2 & 3;
        int which = r2 >> 2;            // 0 = Wih, 1 = Whh
        int m3  = g / 64;               // gate 0=r 1=z 2=n
        int col = g - m3 * 64;
        const float* W = which ? Whh : Wih;
        v = W[(size_t)l * GH * 192 + k * 192 + g];
        v *= (m3 == 2) ? P2LOG2E : NLOG2E;
        int jt = col >> 4, c = col & 15;
        int mat  = which * 3 + m3;
        int rest = (l * 6 + mat) * 4 + jt;
        int kc = k >> 5, j = k & 7, lane = ((k >> 3) & 3) * 16 + c;
        dest = rest * 1024 + kc * 512 + lane * 8 + j;
    } else {
        // Epilogue weights: soW then s2sW, row-major (coalesced)
        int e   = gid - 98304;
        int col = e & 63;
        int k   = (e >> 6) & 63;
        int m2  = e >> 12;              // 0 = soW, 1 = s2sW
        v = (m2 ? s2sW : soW)[k * 64 + col];
        if (m2 && col < 32) v *= NLOG2E;      // A_s sigmoid half
        int jt = col >> 4, c = col & 15;
        int rest = 96 + m2 * 4 + jt;
        int kc = k >> 5, j = k & 7, lane = ((k >> 3) & 3) * 16 + c;
        dest = rest * 1024 + kc * 512 + lane * 8 + j;
    }
    wsW[dest] = (unsigned short)f2bf_rne(v);
}

// LAYER-PIPELINED kernel with FORCED register-resident weights (R6 structure
// + asm pinning). Block = 8 waves (512 thr); wave w -> (layer l = w>>1,
// col-half hg = w&1 owning col-groups 2hg, 2hg+1). 4 GRU layers run
// concurrently, staggered by one t-step: tick tau processes t = tau - l for
// layer l; 35 ticks instead of 128 barrier-steps. Each wave's 24 weight
// B-frags + 8 bias vectors are passed through asm identity ops after load:
// an asm output CANNOT be rematerialized, so the compiler must keep them in
// VGPRs across the tick loop (R4/R5/R6 all silently re-loaded weights from
// L2 every tick when VGPR-clamped - R6's 7800-cycle tick). Inter-layer h
// flows through 2-slot parity buffers `bnd`; recurrence through per-layer
// 2-slot `hrec`; one barrier per tick. Layer-0 inputs built on the fly from
// xs + staged siW/sib (bit-identical to the staged pack_trunc path).
// Per-element math order identical to the verified R1 kernel.
__global__ __launch_bounds__(512, 2) void slowfast_fused(
    const float* __restrict__ x,
    const float* __restrict__ siW,  const float* __restrict__ sib,
    const float* __restrict__ bih,  const float* __restrict__ bhh,
    const float* __restrict__ sob,  const float* __restrict__ s2sb,
    const float* __restrict__ finW, const float* __restrict__ finb,
    const float* __restrict__ foutW, const float* __restrict__ foutb,
    const unsigned short* __restrict__ wsW,
    float* __restrict__ out,
    int T, int ns, int BS)
{
    __shared__ __align__(16) unsigned short bnd[3 * 2 * 1024];   // 12 KB
    __shared__ __align__(16) unsigned short hrec[4 * 2 * 1024];  // 16 KB
    __shared__ __align__(16) unsigned short hfin[1024];          // 2 KB
    __shared__ float xs[16 * 33];    // x windows (pad-33)
    __shared__ float AG[16 * 65];    // A_s | g_s staging (pad-65)
    __shared__ __align__(16) float swS[64], sbS[64];   // siW/sib staging

    const int tid  = threadIdx.x;
    const int lane = tid & 63;
    const int w    = tid >> 6;       // 0..7
    const int l    = w >> 1;         // layer owned by this wave
    const int hg   = w & 1;          // half: col-groups 2hg, 2hg+1
    const int c    = lane & 15;
    const int quad = lane >> 4;
    const int seqbase = blockIdx.x * 16;
    const uint4* wf = reinterpret_cast<const uint4*>(wsW);

    // ---- stage x windows (512 entries, one per thread) + siW/sib ----
    {
        int seq = tid >> 5, t = tid & 31;
        int q = seqbase + seq; if (q > BS - 1) q = BS - 1;
        int b  = (q >= ns) ? 1 : 0;
        int si = q - b * ns;
        xs[seq * 33 + t] = x[b * T + si * DS + t];
    }
    if (tid < 64) { swS[tid] = siW[tid]; sbS[tid] = sib[tid]; }

    // ---- per-wave weight fragments: 2 groups x 6 mats x 2 kc = 24 frags
    bf16x8 BiR[2][2], BiZ[2][2], BiN[2][2], BhR[2][2], BhZ[2][2], BhN[2][2];
    #pragma unroll
    for (int g = 0; g < 2; ++g) {
        int jt2 = hg * 2 + g;
        #pragma unroll
        for (int kc = 0; kc < 2; ++kc) {
            int base = (l * 24 + jt2) * 128 + kc * 64 + lane;  // mat stride 512
            BiR[g][kc] = as_frag(wf[base]);
            BiZ[g][kc] = as_frag(wf[base + 512]);
            BiN[g][kc] = as_frag(wf[base + 1024]);
            BhR[g][kc] = as_frag(wf[base + 1536]);
            BhZ[g][kc] = as_frag(wf[base + 2048]);
            BhN[g][kc] = as_frag(wf[base + 2560]);
        }
    }
    // biases carry the same folded scales
    f32x4 vbR[2], vbZ[2], vbNI[2], vbNH[2];
    #pragma unroll
    for (int g = 0; g < 2; ++g) {
        int col2 = (hg * 2 + g) * 16 + c;
        float bRs  = NLOG2E  * (bih[l * 192 + col2]      + bhh[l * 192 + col2]);
        float bZs  = NLOG2E  * (bih[l * 192 + 64 + col2] + bhh[l * 192 + 64 + col2]);
        float bNIs = P2LOG2E * bih[l * 192 + 128 + col2];
        float bNHs = P2LOG2E * bhh[l * 192 + 128 + col2];
        vbR[g]  = (f32x4){bRs,  bRs,  bRs,  bRs};
        vbZ[g]  = (f32x4){bZs,  bZs,  bZs,  bZs};
        vbNI[g] = (f32x4){bNIs, bNIs, bNIs, bNIs};
        vbNH[g] = (f32x4){bNHs, bNHs, bNHs, bNHs};
    }

    // PIN weights + biases into VGPRs: asm outputs cannot be rematerialized,
    // so the tick loop below cannot re-load them from memory (rule-17 trick).
    #pragma unroll
    for (int g = 0; g < 2; ++g) {
        #pragma unroll
        for (int kc = 0; kc < 2; ++kc) {
            asm volatile("" : "+v"(BiR[g][kc]), "+v"(BiZ[g][kc]), "+v"(BiN[g][kc]));
            asm volatile("" : "+v"(BhR[g][kc]), "+v"(BhZ[g][kc]), "+v"(BhN[g][kc]));
        }
        asm volatile("" : "+v"(vbR[g]), "+v"(vbZ[g]), "+v"(vbNI[g]), "+v"(vbNH[g]));
    }

    // hoisted write indices: per group, this lane's 4 (row,col) elements
    int wIdxG[2][4];
    #pragma unroll
    for (int g = 0; g < 2; ++g) {
        int colg = (hg * 2 + g) * 16 + c;
        #pragma unroll
        for (int i = 0; i < 4; ++i) {
            int row = quad * 4 + i;
            wIdxG[g][i] = (row << 6) + ((((colg >> 3) ^ (row & 7))) << 3) + (colg & 7);
        }
    }

    float hprev[2][4] = {{0.f,0.f,0.f,0.f},{0.f,0.f,0.f,0.f}};
    const float4* sw4 = reinterpret_cast<const float4*>(swS);
    const float4* sb4 = reinterpret_cast<const float4*>(sbS);

    // ---- pipelined tick loop: 32 steps + 3 fill ticks ----
    #pragma unroll 1
    for (int tau = 0; tau < 35; ++tau) {
        __syncthreads();                       // one barrier per tick
        int t = tau - l;
        if (t < 0 || t >= 32) continue;        // wave-uniform; barrier already hit

        bf16x8 a0, a1;
        if (l == 0) {
            // on-the-fly layer-0 input: relu(x*siW+sib), bits identical to
            // the staged pack_trunc path
            float xv = xs[c * 33 + t];
            float4 wA = sw4[quad * 2],     wB = sw4[quad * 2 + 1];
            float4 bA = sb4[quad * 2],     bB = sb4[quad * 2 + 1];
            float4 wC = sw4[8 + quad * 2], wD = sw4[8 + quad * 2 + 1];
            float4 bC = sb4[8 + quad * 2], bD = sb4[8 + quad * 2 + 1];
            uint4 u;
            u.x = pack_trunc(fmaxf(fmaf(xv, wA.x, bA.x), 0.f),
                             fmaxf(fmaf(xv, wA.y, bA.y), 0.f));
            u.y = pack_trunc(fmaxf(fmaf(xv, wA.z, bA.z), 0.f),
                             fmaxf(fmaf(xv, wA.w, bA.w), 0.f));
            u.z = pack_trunc(fmaxf(fmaf(xv, wB.x, bB.x), 0.f),
                             fmaxf(fmaf(xv, wB.y, bB.y), 0.f));
            u.w = pack_trunc(fmaxf(fmaf(xv, wB.z, bB.z), 0.f),
                             fmaxf(fmaf(xv, wB.w, bB.w), 0.f));
            a0 = as_frag(u);
            u.x = pack_trunc(fmaxf(fmaf(xv, wC.x, bC.x), 0.f),
                             fmaxf(fmaf(xv, wC.y, bC.y), 0.f));
            u.y = pack_trunc(fmaxf(fmaf(xv, wC.z, bC.z), 0.f),
                             fmaxf(fmaf(xv, wC.w, bC.w), 0.f));
            u.z = pack_trunc(fmaxf(fmaf(xv, wD.x, bD.x), 0.f),
                             fmaxf(fmaf(xv, wD.y, bD.y), 0.f));
            u.w = pack_trunc(fmaxf(fmaf(xv, wD.z, bD.z), 0.f),
                             fmaxf(fmaf(xv, wD.w, bD.w), 0.f));
            a1 = as_frag(u);
        } else {
            const unsigned short* src = bnd + (((l - 1) << 1) + (t & 1)) * 1024;
            a0 = ld_afrag(src, c, quad, 0);
            a1 = ld_afrag(src, c, quad, 1);
        }

        // ih MFMAs, both groups (independent chains; weights in registers)
        f32x4 aR[2], aZ[2], aNI[2], aNH[2];
        #pragma unroll
        for (int g = 0; g < 2; ++g) {
            aR[g]  = MFMA16(a0, BiR[g][0], vbR[g]);
            aZ[g]  = MFMA16(a0, BiZ[g][0], vbZ[g]);
            aNI[g] = MFMA16(a0, BiN[g][0], vbNI[g]);
            aR[g]  = MFMA16(a1, BiR[g][1], aR[g]);
            aZ[g]  = MFMA16(a1, BiZ[g][1], aZ[g]);
            aNI[g] = MFMA16(a1, BiN[g][1], aNI[g]);
            aNH[g] = vbNH[g];
        }
        if (t > 0) {
            const unsigned short* hb = hrec + ((l << 1) + ((t - 1) & 1)) * 1024;
            bf16x8 h0 = ld_afrag(hb, c, quad, 0);   // pre-relu recurrent
            bf16x8 h1 = ld_afrag(hb, c, quad, 1);
            #pragma unroll
            for (int g = 0; g < 2; ++g) {
                aR[g]  = MFMA16(h0, BhR[g][0], aR[g]);
                aZ[g]  = MFMA16(h0, BhZ[g][0], aZ[g]);
                aNH[g] = MFMA16(h0, BhN[g][0], aNH[g]);
                aR[g]  = MFMA16(h1, BhR[g][1], aR[g]);
                aZ[g]  = MFMA16(h1, BhZ[g][1], aZ[g]);
                aNH[g] = MFMA16(h1, BhN[g][1], aNH[g]);
            }
        }
        unsigned short* wr = hrec + ((l << 1) + (t & 1)) * 1024;
        unsigned short* wb = (l < 3) ? (bnd + ((l << 1) + (t & 1)) * 1024)
                                     : hfin;   // l=3: only t=31 survives (E1)
        #pragma unroll
        for (int g = 0; g < 2; ++g) {
            #pragma unroll
            for (int i = 0; i < 4; ++i) {
                // scales folded into weights: exp2 directly on accumulators
                float r  = __builtin_amdgcn_rcpf(1.0f + __builtin_amdgcn_exp2f(aR[g][i]));
                float z  = __builtin_amdgcn_rcpf(1.0f + __builtin_amdgcn_exp2f(aZ[g][i]));
                float e  = __builtin_amdgcn_exp2f(fmaf(r, aNH[g][i], aNI[g][i]));
                float n  = fmaf(-2.0f, __builtin_amdgcn_rcpf(e + 1.0f), 1.0f);
                float hn = fmaf(z, hprev[g][i] - n, n);
                hprev[g][i] = hn;
                wr[wIdxG[g][i]] = f2bf_h(hn);                   // pre-relu
                wb[wIdxG[g][i]] = f2bf_h(fmaxf(hn, 0.0f));      // relu'd
            }
        }
    }
    __syncthreads();

    // ---- fused epilogue (waves 0-3 compute; barriers are block-uniform) ----
    f32x4 accS;
    bf16x8 Bso[2], Bs2[2];
    int wIdxE[4];
    const int jt = w;               // epilogue col-group for waves 0-3
    const int colE = jt * 16 + c;
    if (w < 4) {   // E1: slow_feat = relu(h3[31]) @ soW + sob
        #pragma unroll
        for (int i = 0; i < 4; ++i) {
            int row = quad * 4 + i;
            wIdxE[i] = (row << 6) + ((((colE >> 3) ^ (row & 7))) << 3) + (colE & 7);
        }
        bf16x8 e0 = ld_afrag(hfin, c, quad, 0);
        bf16x8 e1 = ld_afrag(hfin, c, quad, 1);
        #pragma unroll
        for (int kc = 0; kc < 2; ++kc) {
            Bso[kc] = as_frag(wf[(96 + jt)  * 128 + kc * 64 + lane]);
            Bs2[kc] = as_frag(wf[(100 + jt) * 128 + kc * 64 + lane]);
        }
        float sb = sob[colE];
        accS = (f32x4){sb, sb, sb, sb};
        accS = MFMA16(e0, Bso[0], accS);
        accS = MFMA16(e1, Bso[1], accS);
    }
    __syncthreads();                 // all E1 reads of hfin done before rewrite
    if (w < 4) {
        #pragma unroll
        for (int i = 0; i < 4; ++i)
            hfin[wIdxE[i]] = f2bf_h(accS[i]);   // stage slow_feat
    }
    __syncthreads();
    if (w < 4) {   // E2: eps = sf @ s2sW + s2sb -> A_s | g_s
        bf16x8 s0 = ld_afrag(hfin, c, quad, 0);
        bf16x8 s1 = ld_afrag(hfin, c, quad, 1);
        float eb = (jt < 2) ? NLOG2E * s2sb[colE] : s2sb[colE];
        f32x4 accE = (f32x4){eb, eb, eb, eb};
        accE = MFMA16(s0, Bs2[0], accE);
        accE = MFMA16(s1, Bs2[1], accE);
        #pragma unroll
        for (int i = 0; i < 4; ++i) {
            int row = quad * 4 + i;
            float v = accE[i];
            AG[row * 65 + colE] = (jt < 2)
                ? __builtin_amdgcn_rcpf(1.0f + __builtin_amdgcn_exp2f(v)) : v;
        }
    }
    __syncthreads();
    // E3: fast diagonal SSM + overlap-add (16 frames x 32 ch, single pass)
    {
        int fch   = tid & 31;
        int frame = tid >> 5;
        if (frame < 16) {
            int q = seqbase + frame;
            if (q < BS) {        // skip duplicated clamp frames (no double-add)
                float Gfw = finW[fch], Gbw = finb[fch];
                float cFo = foutW[fch], cfb = foutb[0];
                int b  = (q >= ns) ? 1 : 0;
                int fi = q - b * ns;
                float cA = AG[frame * 65 + fch];
                float cG = AG[frame * 65 + 32 + fch];
                float Gf = Gfw * cG;
                float Gb = Gbw * cG;
                float h = 0.0f;
                const float* xrow = xs + frame * 33;
                float* op = out + (size_t)b * T + fi * DS;
                #pragma unroll 1
                for (int t = 0; t < LS; ++t) {
                    h = fmaf(cA, h, fmaf(xrow[t], Gf, Gb));
                    float s = h * cFo;
                    s += __shfl_xor(s, 1);
                    s += __shfl_xor(s, 2);
                    s += __shfl_xor(s, 4);
                    s += __shfl_xor(s, 8);
                    s += __shfl_xor(s, 16);
                    if (fch == 0) atomicAdd(&op[t], s + cfb);
                }
            }
        }
    }
}

extern "C" void kernel_launch(void* const* d_in, const int* in_sizes, int n_in,
                              void* d_out, int out_size, void* d_ws, size_t ws_size,
                              hipStream_t stream)
{
    (void)n_in; (void)ws_size;
    const float* x     = (const float*)d_in[0];
    const float* siW   = (const float*)d_in[1];
    const float* sib   = (const float*)d_in[2];
    const float* Wih   = (const float*)d_in[3];
    const float* Whh   = (const float*)d_in[4];
    const float* bih   = (const float*)d_in[5];
    const float* bhh   = (const float*)d_in[6];
    const float* soW   = (const float*)d_in[7];
    const float* sob   = (const float*)d_in[8];
    const float* s2sW  = (const float*)d_in[9];
    const float* s2sb  = (const float*)d_in[10];
    const float* finW  = (const float*)d_in[11];
    const float* finb  = (const float*)d_in[12];
    const float* foutW = (const float*)d_in[13];
    const float* foutb = (const float*)d_in[14];

    int T  = in_sizes[0] / 2;          // B = 2
    int ns = (T - LS) / DS + 1;        // 3999
    int BS = 2 * ns;                   // 7998
    int nblocks = (BS + 15) / 16;      // 500

    unsigned short* wsW = (unsigned short*)d_ws;   // 104*1024 bf16 = 208 KB

    // prep also zeroes `out` (separate memset dispatch removed)
    prep_weights<<<dim3(416), dim3(256), 0, stream>>>(
        Wih, Whh, soW, s2sW, wsW, (float*)d_out, out_size);

    slowfast_fused<<<dim3(nblocks), dim3(512), 0, stream>>>(
        x, siW, sib, bih, bhh, sob, s2sb, finW, finb, foutW, foutb,
        wsW, (float*)d_out, T, ns, BS);
}

// Round 11
// 172.375 us; speedup vs baseline: 1.0633x; 1.0633x over previous
//
#include <hip/hip_runtime.h>

#define GH 64
#define LS 32
#define HF 32
#define DS 16

// transcendental folding constants (exact fp32 rescale of weights at prep)
#define NLOG2E -1.4426950408889634f   // r,z columns:  sigm(x)=rcp(1+exp2(-log2e*x))
#define P2LOG2E 2.8853900817779268f   // n columns:    tanh(x)=1-2*rcp(exp2(2log2e*x)+1)

typedef short bf16x8 __attribute__((ext_vector_type(8)));
typedef float f32x4 __attribute__((ext_vector_type(4)));

#define MFMA16(a, b, c) __builtin_amdgcn_mfma_f32_16x16x32_bf16(a, b, c, 0, 0, 0)

__device__ __forceinline__ unsigned int f2bf_rne(float f) {
    unsigned int u = __float_as_uint(f);
    return (u + 0x7FFFu + ((u >> 16) & 1u)) >> 16;   // RNE (prep kernel only)
}
__device__ __forceinline__ unsigned short f2bf_h(float f) {
    return (unsigned short)((__float_as_uint(f) + 0x8000u) >> 16);  // half-up
}
__device__ __forceinline__ unsigned int pack_trunc(float v0, float v1) {
    return __builtin_amdgcn_perm(__float_as_uint(v1), __float_as_uint(v0),
                                 0x07060302u);   // (bf16(v1)<<16)|bf16(v0)
}
__device__ __forceinline__ bf16x8 as_frag(uint4 u) {
    union { uint4 a; bf16x8 b; } cv; cv.a = u; return cv.b;
}

// A-fragment from one 16x64 bf16 slot, XOR-swizzled 16B blocks:
// (seq,ch) at seq*64 + (((ch>>3)^(seq&7))<<3) + (ch&7).
__device__ __forceinline__ bf16x8 ld_afrag(const unsigned short* slot, int m,
                                           int quad, int half) {
    int b   = half * 4 + quad;
    int idx = (m << 6) + ((b ^ (m & 7)) << 3);
    return as_frag(*reinterpret_cast<const uint4*>(slot + idx));
}

// ---- prep (read-coalesced, verified R2): fp32 weights -> bf16 MFMA
// B-fragments, fragment-ordered, transcendental scales FOLDED IN. One
// thread per SOURCE element (coalesced reads, scattered fire-and-forget
// writes). Also zeroes `out` (removes a memset dispatch).
__global__ __launch_bounds__(256) void prep_weights(
    const float* __restrict__ Wih, const float* __restrict__ Whh,
    const float* __restrict__ soW, const float* __restrict__ s2sW,
    unsigned short* __restrict__ wsW,
    float* __restrict__ out, int out_n)
{
    int gid = blockIdx.x * 256 + threadIdx.x;
    int nthreads = gridDim.x * 256;

    // ---- zero the output buffer (float4 grid-stride + scalar tail) ----
    {
        float4* out4 = reinterpret_cast<float4*>(out);
        int n4 = out_n >> 2;
        for (int i = gid; i < n4; i += nthreads)
            out4[i] = make_float4(0.f, 0.f, 0.f, 0.f);
        int tail = out_n & 3;
        if (gid < tail) out[n4 * 4 + gid] = 0.0f;
    }

    if (gid >= 104 * 1024) return;

    float v;
    int dest;
    if (gid < 98304) {
        // GRU weights: source order (which, l, k, g) with g fastest (coalesced)
        int g     = gid % 192;
        int r1    = gid / 192;          // (which,l,k)
        int k     = r1 & 63;
        int r2    = r1 >> 6;            // (which,l)
        int l     = r2 & 3;
        int which = r2 >> 2;            // 0 = Wih, 1 = Whh
        int m3  = g / 64;               // gate 0=r 1=z 2=n
        int col = g - m3 * 64;
        const float* W = which ? Whh : Wih;
        v = W[(size_t)l * GH * 192 + k * 192 + g];
        v *= (m3 == 2) ? P2LOG2E : NLOG2E;
        int jt = col >> 4, c = col & 15;
        int mat  = which * 3 + m3;
        int rest = (l * 6 + mat) * 4 + jt;
        int kc = k >> 5, j = k & 7, lane = ((k >> 3) & 3) * 16 + c;
        dest = rest * 1024 + kc * 512 + lane * 8 + j;
    } else {
        // Epilogue weights: soW then s2sW, row-major (coalesced)
        int e   = gid - 98304;
        int col = e & 63;
        int k   = (e >> 6) & 63;
        int m2  = e >> 12;              // 0 = soW, 1 = s2sW
        v = (m2 ? s2sW : soW)[k * 64 + col];
        if (m2 && col < 32) v *= NLOG2E;      // A_s sigmoid half
        int jt = col >> 4, c = col & 15;
        int rest = 96 + m2 * 4 + jt;
        int kc = k >> 5, j = k & 7, lane = ((k >> 3) & 3) * 16 + c;
        dest = rest * 1024 + kc * 512 + lane * 8 + j;
    }
    wsW[dest] = (unsigned short)f2bf_rne(v);
}

// Block = 4 waves x 64 (wave jt owns gate cols [jt*16,jt*16+16)); 16 seqs.
// hseq: RELU'D h (next-layer input), in-place across layers, 64 KB.
// hrec: PRE-relu h, 2-slot ping-pong (recurrence needs only t-1), 4 KB.
// One barrier/step; a(t+1) prefetched pre-barrier; t-loop unroll-2 makes the
// ping-pong parity static. Weights pre-scaled so exp2 applies directly to
// the MFMA accumulator (no per-element muls). Fused epilogue + fast SSM.
// TERMINAL KERNEL: best-measured configuration (R1 fused + R2 prep). Six
// structural alternatives (global-hseq, 16-wave pipeline, dual-chain, 8-wave
// pinned x2, MFMA hoist, in-kernel convert) all measured slower; the
// register allocator refuses >~108 live VGPRs across the barrier loop, which
// forecloses the weight-resident no-barrier designs.
__global__ __launch_bounds__(256, 2) void slowfast_fused(
    const float* __restrict__ x,
    const float* __restrict__ siW,  const float* __restrict__ sib,
    const float* __restrict__ bih,  const float* __restrict__ bhh,
    const float* __restrict__ sob,  const float* __restrict__ s2sb,
    const float* __restrict__ finW, const float* __restrict__ finb,
    const float* __restrict__ foutW, const float* __restrict__ foutb,
    const unsigned short* __restrict__ wsW,
    float* __restrict__ out,
    int T, int ns, int BS)
{
    __shared__ __align__(16) unsigned short hseq[LS * 16 * 64];  // 64 KB
    __shared__ __align__(16) unsigned short hrec[2 * 16 * 64];   // 4 KB
    __shared__ float xs[16 * 33];    // x windows (pad-33)
    __shared__ float AG[16 * 65];    // A_s | g_s staging (pad-65)

    const int tid  = threadIdx.x;
    const int lane = tid & 63;
    const int jt   = tid >> 6;
    const int c    = lane & 15;
    const int quad = lane >> 4;
    const int col  = jt * 16 + c;
    const int seqbase = blockIdx.x * 16;
    const uint4* wf = reinterpret_cast<const uint4*>(wsW);

    // ---- stage x windows ----
    for (int p = tid; p < 512; p += 256) {           // p = seq*32 + t
        int seq = p >> 5, t = p & 31;
        int q = seqbase + seq; if (q > BS - 1) q = BS - 1;
        int b  = (q >= ns) ? 1 : 0;
        int si = q - b * ns;
        xs[seq * 33 + t] = x[b * T + si * DS + t];
    }
    __syncthreads();

    // ---- layer-0 inputs: relu(x*siW+sib), packed dword writes, conflict-free
    {
        int chp = tid & 31;          // channel pair id
        int grp = tid >> 5;          // 8 groups over 512 (seq,t) pairs
        int ch  = chp << 1;
        float w0 = siW[ch], w1 = siW[ch + 1];
        float b0 = sib[ch], b1 = sib[ch + 1];
        #pragma unroll 4
        for (int it = 0; it < 64; ++it) {
            int p = grp + (it << 3);
            int s = p >> 5, t = p & 31;
            float xv = xs[s * 33 + t];
            float v0 = fmaxf(fmaf(xv, w0, b0), 0.0f);
            float v1 = fmaxf(fmaf(xv, w1, b1), 0.0f);
            int idx = (t << 10) + (s << 6) + ((((ch >> 3) ^ (s & 7))) << 3) + (ch & 7);
            *reinterpret_cast<unsigned int*>(&hseq[idx]) = pack_trunc(v0, v1);
        }
    }

    // hoisted write indices for this lane's 4 (row,col) gate elements
    int wIdx[4];
    #pragma unroll
    for (int i = 0; i < 4; ++i) {
        int row = quad * 4 + i;
        wIdx[i] = (row << 6) + ((((col >> 3) ^ (row & 7))) << 3) + (col & 7);
    }

    __syncthreads();

    bf16x8 a0 = ld_afrag(hseq, c, quad, 0);   // layer-0 input, t=0 (relu'd)
    bf16x8 a1 = ld_afrag(hseq, c, quad, 1);

    for (int l = 0; l < 4; ++l) {
        // 12 coalesced 16B fragment loads from prepped (pre-scaled) ws
        bf16x8 BiR[2], BiZ[2], BiN[2], BhR[2], BhZ[2], BhN[2];
        #pragma unroll
        for (int kc = 0; kc < 2; ++kc) {
            int base = (l * 6 * 4 + jt) * 128 + kc * 64 + lane;  // mat stride 512
            BiR[kc] = as_frag(wf[base]);
            BiZ[kc] = as_frag(wf[base + 512]);
            BiN[kc] = as_frag(wf[base + 1024]);
            BhR[kc] = as_frag(wf[base + 1536]);
            BhZ[kc] = as_frag(wf[base + 2048]);
            BhN[kc] = as_frag(wf[base + 2560]);
        }
        // biases carry the same folded scales
        float bRs  = NLOG2E  * (bih[l * 192 + col]      + bhh[l * 192 + col]);
        float bZs  = NLOG2E  * (bih[l * 192 + 64 + col] + bhh[l * 192 + 64 + col]);
        float bNIs = P2LOG2E * bih[l * 192 + 128 + col];  // n-gate ih/hh separate:
        float bNHs = P2LOG2E * bhh[l * 192 + 128 + col];  // tanh(xg_n + r*hg_n)
        const f32x4 vbR  = (f32x4){bRs,  bRs,  bRs,  bRs};
        const f32x4 vbZ  = (f32x4){bZs,  bZs,  bZs,  bZs};
        const f32x4 vbNI = (f32x4){bNIs, bNIs, bNIs, bNIs};
        const f32x4 vbNH = (f32x4){bNHs, bNHs, bNHs, bNHs};

        float hprev[4] = {0.0f, 0.0f, 0.0f, 0.0f};

        #pragma unroll 2
        for (int t = 0; t < LS; ++t) {
            f32x4 aR  = MFMA16(a0, BiR[0], vbR);
            f32x4 aZ  = MFMA16(a0, BiZ[0], vbZ);
            f32x4 aNI = MFMA16(a0, BiN[0], vbNI);
            aR  = MFMA16(a1, BiR[1], aR);
            aZ  = MFMA16(a1, BiZ[1], aZ);
            aNI = MFMA16(a1, BiN[1], aNI);
            f32x4 aNH = vbNH;
            if (t > 0) {
                const unsigned short* hb = hrec + (((t - 1) & 1) << 10);
                bf16x8 h0 = ld_afrag(hb, c, quad, 0);   // pre-relu recurrent
                bf16x8 h1 = ld_afrag(hb, c, quad, 1);
                aR  = MFMA16(h0, BhR[0], aR);
                aZ  = MFMA16(h0, BhZ[0], aZ);
                aNH = MFMA16(h0, BhN[0], aNH);
                aR  = MFMA16(h1, BhR[1], aR);
                aZ  = MFMA16(h1, BhZ[1], aZ);
                aNH = MFMA16(h1, BhN[1], aNH);
            }
            unsigned short* wb = hseq + (t << 10);
            unsigned short* wr = hrec + ((t & 1) << 10);
            #pragma unroll
            for (int i = 0; i < 4; ++i) {
                // scales folded into weights: exp2 directly on accumulators
                float r  = __builtin_amdgcn_rcpf(1.0f + __builtin_amdgcn_exp2f(aR[i]));
                float z  = __builtin_amdgcn_rcpf(1.0f + __builtin_amdgcn_exp2f(aZ[i]));
                float e  = __builtin_amdgcn_exp2f(fmaf(r, aNH[i], aNI[i]));
                float n  = fmaf(-2.0f, __builtin_amdgcn_rcpf(e + 1.0f), 1.0f);
                float hn = fmaf(z, hprev[i] - n, n);
                hprev[i] = hn;
                wr[wIdx[i]] = f2bf_h(hn);                   // pre-relu (recurrence)
                wb[wIdx[i]] = f2bf_h(fmaxf(hn, 0.0f));      // relu'd (next layer)
            }
            // prefetch next input: slot t+1 untouched this step; at t=31 slot 0
            // already holds this layer's relu'd t=0 output = next layer's input
            const unsigned short* nb = hseq + (((t + 1) & 31) << 10);
            a0 = ld_afrag(nb, c, quad, 0);
            a1 = ld_afrag(nb, c, quad, 1);
            __syncthreads();
        }
    }

    // ---- fused epilogue ----
    {   // E1: slow_feat = hseq[31] (already relu'd) @ soW + sob -> stage slot 0
        bf16x8 e0 = ld_afrag(hseq + (31 << 10), c, quad, 0);
        bf16x8 e1 = ld_afrag(hseq + (31 << 10), c, quad, 1);
        bf16x8 Bso[2], Bs2[2];
        #pragma unroll
        for (int kc = 0; kc < 2; ++kc) {
            Bso[kc] = as_frag(wf[(96 + jt)  * 128 + kc * 64 + lane]);
            Bs2[kc] = as_frag(wf[(100 + jt) * 128 + kc * 64 + lane]);
        }
        float sb = sob[col];
        f32x4 accS = (f32x4){sb, sb, sb, sb};
        accS = MFMA16(e0, Bso[0], accS);
        accS = MFMA16(e1, Bso[1], accS);
        #pragma unroll
        for (int i = 0; i < 4; ++i)
            hseq[wIdx[i]] = f2bf_h(accS[i]);     // slot 0 dead: stage slow_feat
        __syncthreads();
        // E2: eps = sf @ s2sW + s2sb -> A_s | g_s (A half pre-scaled by -log2e)
        bf16x8 s0 = ld_afrag(hseq, c, quad, 0);
        bf16x8 s1 = ld_afrag(hseq, c, quad, 1);
        float eb = (jt < 2) ? NLOG2E * s2sb[col] : s2sb[col];
        f32x4 accE = (f32x4){eb, eb, eb, eb};
        accE = MFMA16(s0, Bs2[0], accE);
        accE = MFMA16(s1, Bs2[1], accE);
        #pragma unroll
        for (int i = 0; i < 4; ++i) {
            int row = quad * 4 + i;
            float v = accE[i];
            AG[row * 65 + col] = (jt < 2)
                ? __builtin_amdgcn_rcpf(1.0f + __builtin_amdgcn_exp2f(v)) : v;
        }
    }
    __syncthreads();
    // E3: fast diagonal SSM + overlap-add (16 frames x 32 ch, 2 passes)
    {
        int fch = tid & 31;
        float Gfw = finW[fch], Gbw = finb[fch], cFo = foutW[fch], cfb = foutb[0];
        #pragma unroll
        for (int half = 0; half < 2; ++half) {
            int frame = half * 8 + (tid >> 5);
            int q = seqbase + frame;
            if (q < BS) {        // skip duplicated clamp frames (no double-add)
                int b  = (q >= ns) ? 1 : 0;
                int fi = q - b * ns;
                float cA = AG[frame * 65 + fch];
                float cG = AG[frame * 65 + 32 + fch];
                float Gf = Gfw * cG;
                float Gb = Gbw * cG;
                float h = 0.0f;
                const float* xrow = xs + frame * 33;
                float* op = out + (size_t)b * T + fi * DS;
                #pragma unroll 1
                for (int t = 0; t < LS; ++t) {
                    h = fmaf(cA, h, fmaf(xrow[t], Gf, Gb));
                    float s = h * cFo;
                    s += __shfl_xor(s, 1);
                    s += __shfl_xor(s, 2);
                    s += __shfl_xor(s, 4);
                    s += __shfl_xor(s, 8);
                    s += __shfl_xor(s, 16);
                    if (fch == 0) atomicAdd(&op[t], s + cfb);
                }
            }
        }
    }
}

extern "C" void kernel_launch(void* const* d_in, const int* in_sizes, int n_in,
                              void* d_out, int out_size, void* d_ws, size_t ws_size,
                              hipStream_t stream)
{
    (void)n_in; (void)ws_size;
    const float* x     = (const float*)d_in[0];
    const float* siW   = (const float*)d_in[1];
    const float* sib   = (const float*)d_in[2];
    const float* Wih   = (const float*)d_in[3];
    const float* Whh   = (const float*)d_in[4];
    const float* bih   = (const float*)d_in[5];
    const float* bhh   = (const float*)d_in[6];
    const float* soW   = (const float*)d_in[7];
    const float* sob   = (const float*)d_in[8];
    const float* s2sW  = (const float*)d_in[9];
    const float* s2sb  = (const float*)d_in[10];
    const float* finW  = (const float*)d_in[11];
    const float* finb  = (const float*)d_in[12];
    const float* foutW = (const float*)d_in[13];
    const float* foutb = (const float*)d_in[14];

    int T  = in_sizes[0] / 2;          // B = 2
    int ns = (T - LS) / DS + 1;        // 3999
    int BS = 2 * ns;                   // 7998

    unsigned short* wsW = (unsigned short*)d_ws;   // 104*1024 bf16 = 208 KB

    // prep also zeroes `out` (separate memset dispatch removed)
    prep_weights<<<dim3(416), dim3(256), 0, stream>>>(
        Wih, Whh, soW, s2sW, wsW, (float*)d_out, out_size);

    slowfast_fused<<<dim3((BS + 15) / 16), dim3(256), 0, stream>>>(
        x, siW, sib, bih, bhh, sob, s2sb, finW, finb, foutW, foutb,
        wsW, (float*)d_out, T, ns, BS);
}